// Round 3
// baseline (1094.562 us; speedup 1.0000x reference)
//
#include <hip/hip_runtime.h>
#include <math.h>

// Problem constants (from reference)
#define HID 64      // H*C
#define NH 4
#define NC 16
#define EDIM 16
#define OUTD 128
#define NEG 0.2f

// CSR slot record: {src, attr_ptr_lo, attr_ptr_hi, unused}
// Slot offs[d] is the self-loop (attr -> la row d); slots offs[d]+1.. are in-edges.

// ---------------- CSR build ----------------

__global__ void hist_kernel(const int* __restrict__ dst, int* __restrict__ deg, int E) {
    int e = blockIdx.x * 256 + threadIdx.x;
    if (e < E) atomicAdd(&deg[dst[e]], 1);
}

__global__ void scan_a(const int* __restrict__ deg, int* __restrict__ offs,
                       int* __restrict__ bsum, int n) {
    __shared__ int tmp[1024];
    int i = blockIdx.x * 1024 + threadIdx.x;
    int v = (i < n) ? (deg[i] + 1) : 0;      // +1: self-loop slot
    tmp[threadIdx.x] = v;
    __syncthreads();
    for (int off = 1; off < 1024; off <<= 1) {
        int t = (threadIdx.x >= off) ? tmp[threadIdx.x - off] : 0;
        __syncthreads();
        tmp[threadIdx.x] += t;
        __syncthreads();
    }
    if (i < n) offs[i] = tmp[threadIdx.x] - v;   // exclusive
    if (threadIdx.x == 1023) bsum[blockIdx.x] = tmp[1023];
}

__global__ void scan_b(int* __restrict__ bsum, int* __restrict__ offs, int nb, int n) {
    __shared__ int tmp[1024];
    int v = (threadIdx.x < nb) ? bsum[threadIdx.x] : 0;
    tmp[threadIdx.x] = v;
    __syncthreads();
    for (int off = 1; off < 1024; off <<= 1) {
        int t = (threadIdx.x >= off) ? tmp[threadIdx.x - off] : 0;
        __syncthreads();
        tmp[threadIdx.x] += t;
        __syncthreads();
    }
    if (threadIdx.x < nb) bsum[threadIdx.x] = tmp[threadIdx.x] - v;  // exclusive
    if (threadIdx.x == 1023) offs[n] = tmp[1023];                    // total = E + N
}

__global__ void scan_c(int* __restrict__ offs, const int* __restrict__ bsum, int n) {
    int i = blockIdx.x * 1024 + threadIdx.x;
    if (i < n) offs[i] += bsum[blockIdx.x];
}

__global__ void scatter_kernel(const int* __restrict__ src, const int* __restrict__ dst,
                               const float* __restrict__ ea,
                               const int* __restrict__ offs, int* __restrict__ cursor,
                               int4* __restrict__ csr, int E) {
    int e = blockIdx.x * 256 + threadIdx.x;
    if (e >= E) return;
    int d = dst[e];
    int p = offs[d] + 1 + atomicAdd(&cursor[d], 1);
    uint64_t pa = (uint64_t)(ea + (size_t)e * EDIM);
    int4 rec;
    rec.x = src[e];
    rec.y = (int)(uint32_t)(pa & 0xffffffffu);
    rec.z = (int)(uint32_t)(pa >> 32);
    rec.w = 0;
    csr[p] = rec;
}

// self-loop attr = mean of incoming edge attrs (0 if none); also stamp self slot
__global__ void loopattr_kernel(const int* __restrict__ offs, int4* __restrict__ csr,
                                float* __restrict__ la, int n) {
    int idx = blockIdx.x * 256 + threadIdx.x;
    if (idx >= n * EDIM) return;
    int nd = idx >> 4, k = idx & 15;
    int e0 = offs[nd], e1 = offs[nd + 1];
    int deg = e1 - e0 - 1;
    float s = 0.f;
    for (int j = e0 + 1; j < e1; j++) {
        int4 rec = csr[j];
        const float* ap = (const float*)(((uint64_t)(uint32_t)rec.z << 32) |
                                         (uint32_t)rec.y);
        s += ap[k];
    }
    la[idx] = s / fmaxf((float)deg, 1.0f);
    if (k == 0) {
        uint64_t pa = (uint64_t)(la + (size_t)nd * EDIM);
        int4 rec;
        rec.x = nd;
        rec.y = (int)(uint32_t)(pa & 0xffffffffu);
        rec.z = (int)(uint32_t)(pa >> 32);
        rec.w = 0;
        csr[e0] = rec;
    }
}

// ---------------- dual GEMM: xl = x@Wl+bl, xr = x@Wr+br ----------------

__global__ __launch_bounds__(256)
void dualgemm_kernel(const float* __restrict__ x,
                     const float* __restrict__ Wl, const float* __restrict__ bl,
                     const float* __restrict__ Wr, const float* __restrict__ br,
                     float* __restrict__ xl, float* __restrict__ xr, int n) {
    __shared__ float xs[64 * 65];     // [row][k], pad 65
    __shared__ float ws[64 * 128];    // [k][j]: j<64 -> Wl col, j>=64 -> Wr col
    int tid = threadIdx.x;
    int r0 = blockIdx.x * 64;

#pragma unroll
    for (int t = 0; t < 32; t++) {
        int idx = t * 256 + tid;
        int k = idx >> 7, j = idx & 127;
        ws[idx] = (j < 64) ? Wl[k * 64 + j] : Wr[k * 64 + (j - 64)];
    }
#pragma unroll
    for (int t = 0; t < 16; t++) {
        int idx = t * 256 + tid;
        int r = idx >> 6, c = idx & 63;
        float v = (r0 + r < n) ? x[(r0 + r) * 64 + c] : 0.f;
        xs[r * 65 + c] = v;
    }
    __syncthreads();

    int cg = tid & 31;
    int rg = tid >> 5;

    float acc[8][4];
#pragma unroll
    for (int u = 0; u < 8; u++)
#pragma unroll
        for (int v = 0; v < 4; v++) acc[u][v] = 0.f;

    for (int k = 0; k < 64; k++) {
        float4 wv = *(const float4*)&ws[k * 128 + cg * 4];
        float xv[8];
#pragma unroll
        for (int u = 0; u < 8; u++) xv[u] = xs[(rg * 8 + u) * 65 + k];
#pragma unroll
        for (int u = 0; u < 8; u++) {
            acc[u][0] += xv[u] * wv.x;
            acc[u][1] += xv[u] * wv.y;
            acc[u][2] += xv[u] * wv.z;
            acc[u][3] += xv[u] * wv.w;
        }
    }

    int j0 = cg * 4;
    bool isL = (j0 < 64);
    const float* bp = isL ? bl : br;
    float* op = isL ? xl : xr;
    int jj = isL ? j0 : (j0 - 64);
    float4 bv = *(const float4*)&bp[jj];
#pragma unroll
    for (int u = 0; u < 8; u++) {
        int r = r0 + rg * 8 + u;
        if (r < n) {
            float4 o;
            o.x = acc[u][0] + bv.x; o.y = acc[u][1] + bv.y;
            o.z = acc[u][2] + bv.z; o.w = acc[u][3] + bv.w;
            *(float4*)&op[r * 64 + jj] = o;
        }
    }
}

// ---------------- GATv2 layer: one wave per dst node, online softmax ----------------
// lane = h*16 + c. Branchless loop (self-loop is a CSR slot), 2-edge unroll,
// exp2 domain (att pre-scaled by log2e).

__global__ __launch_bounds__(256)
void gat_kernel(const int* __restrict__ offs, const int4* __restrict__ csr,
                const float* __restrict__ xl, const float* __restrict__ xr,
                const float* __restrict__ We, const float* __restrict__ att,
                const float* __restrict__ bias, float* __restrict__ out, int n) {
    int lane = threadIdx.x & 63;
    int node = blockIdx.x * 4 + (threadIdx.x >> 6);
    node = __builtin_amdgcn_readfirstlane(node);
    if (node >= n) return;

    float wec[16];
#pragma unroll
    for (int k = 0; k < 16; k++) wec[k] = We[k * 64 + lane];
    const float LOG2E = 1.4426950408889634f;
    float attl = att[lane] * LOG2E;
    float xrl = xr[(size_t)node * 64 + lane];

    float M = -1e30f, S = 0.f, acc = 0.f;
    int e0 = __builtin_amdgcn_readfirstlane(offs[node]);
    int e1 = __builtin_amdgcn_readfirstlane(offs[node + 1]);

    int i = e0;
    for (; i + 1 < e1; i += 2) {
        int4 r0 = csr[i];
        int4 r1 = csr[i + 1];
        int s0 = __builtin_amdgcn_readfirstlane(r0.x);
        int s1 = __builtin_amdgcn_readfirstlane(r1.x);
        const float4* ap0 = (const float4*)(
            ((uint64_t)(uint32_t)__builtin_amdgcn_readfirstlane(r0.z) << 32) |
            (uint32_t)__builtin_amdgcn_readfirstlane(r0.y));
        const float4* ap1 = (const float4*)(
            ((uint64_t)(uint32_t)__builtin_amdgcn_readfirstlane(r1.z) << 32) |
            (uint32_t)__builtin_amdgcn_readfirstlane(r1.y));

        float x0 = xl[(size_t)s0 * 64 + lane];
        float x1 = xl[(size_t)s1 * 64 + lane];
        float4 a0 = ap0[0], a1 = ap0[1], a2 = ap0[2], a3 = ap0[3];
        float4 b0 = ap1[0], b1 = ap1[1], b2 = ap1[2], b3 = ap1[3];

        float m0 = x0 + xrl;
        float m1 = x1 + xrl;
        m0 += a0.x*wec[0] + a0.y*wec[1] + a0.z*wec[2] + a0.w*wec[3]
            + a1.x*wec[4] + a1.y*wec[5] + a1.z*wec[6] + a1.w*wec[7]
            + a2.x*wec[8] + a2.y*wec[9] + a2.z*wec[10] + a2.w*wec[11]
            + a3.x*wec[12] + a3.y*wec[13] + a3.z*wec[14] + a3.w*wec[15];
        m1 += b0.x*wec[0] + b0.y*wec[1] + b0.z*wec[2] + b0.w*wec[3]
            + b1.x*wec[4] + b1.y*wec[5] + b1.z*wec[6] + b1.w*wec[7]
            + b2.x*wec[8] + b2.y*wec[9] + b2.z*wec[10] + b2.w*wec[11]
            + b3.x*wec[12] + b3.y*wec[13] + b3.z*wec[14] + b3.w*wec[15];
        m0 = fmaxf(m0, NEG * m0);
        m1 = fmaxf(m1, NEG * m1);
        float p0 = m0 * attl;
        float p1 = m1 * attl;
        // two independent reduce chains (latency overlap)
        p0 += __shfl_xor(p0, 1);  p1 += __shfl_xor(p1, 1);
        p0 += __shfl_xor(p0, 2);  p1 += __shfl_xor(p1, 2);
        p0 += __shfl_xor(p0, 4);  p1 += __shfl_xor(p1, 4);
        p0 += __shfl_xor(p0, 8);  p1 += __shfl_xor(p1, 8);

        float Mn = fmaxf(M, fmaxf(p0, p1));
        float fs = __builtin_amdgcn_exp2f(M - Mn);
        float z0 = __builtin_amdgcn_exp2f(p0 - Mn);
        float z1 = __builtin_amdgcn_exp2f(p1 - Mn);
        S   = S * fs + z0 + z1;
        acc = acc * fs + z0 * x0 + z1 * x1;
        M = Mn;
    }
    if (i < e1) {   // tail (1 edge)
        int4 r0 = csr[i];
        int s0 = __builtin_amdgcn_readfirstlane(r0.x);
        const float4* ap0 = (const float4*)(
            ((uint64_t)(uint32_t)__builtin_amdgcn_readfirstlane(r0.z) << 32) |
            (uint32_t)__builtin_amdgcn_readfirstlane(r0.y));
        float x0 = xl[(size_t)s0 * 64 + lane];
        float4 a0 = ap0[0], a1 = ap0[1], a2 = ap0[2], a3 = ap0[3];
        float m0 = x0 + xrl;
        m0 += a0.x*wec[0] + a0.y*wec[1] + a0.z*wec[2] + a0.w*wec[3]
            + a1.x*wec[4] + a1.y*wec[5] + a1.z*wec[6] + a1.w*wec[7]
            + a2.x*wec[8] + a2.y*wec[9] + a2.z*wec[10] + a2.w*wec[11]
            + a3.x*wec[12] + a3.y*wec[13] + a3.z*wec[14] + a3.w*wec[15];
        m0 = fmaxf(m0, NEG * m0);
        float p0 = m0 * attl;
        p0 += __shfl_xor(p0, 1);
        p0 += __shfl_xor(p0, 2);
        p0 += __shfl_xor(p0, 4);
        p0 += __shfl_xor(p0, 8);
        float Mn = fmaxf(M, p0);
        float fs = __builtin_amdgcn_exp2f(M - Mn);
        float z0 = __builtin_amdgcn_exp2f(p0 - Mn);
        S   = S * fs + z0;
        acc = acc * fs + z0 * x0;
        M = Mn;
    }
    out[(size_t)node * 64 + lane] = fmaxf(acc / S + bias[lane], 0.f);
}

// ---------------- fused pool (batch is sorted) + MLP: one block per graph ----------------

__global__ __launch_bounds__(256)
void pool_mlp_kernel(const float* __restrict__ x, const int* __restrict__ batch, int n,
                     const float* __restrict__ W1, const float* __restrict__ b1,
                     const float* __restrict__ W2, const float* __restrict__ b2,
                     float* __restrict__ out) {
    __shared__ float psum[4][64];
    __shared__ float gv[64];
    __shared__ float hid[128];
    __shared__ int bounds[2];

    int g = blockIdx.x;
    int tid = threadIdx.x;
    int wave = tid >> 6, lane = tid & 63;

    if (tid < 2) {
        int target = g + tid;
        int lo = 0, hi = n;
        while (lo < hi) {
            int mid = (lo + hi) >> 1;
            if (batch[mid] < target) lo = mid + 1; else hi = mid;
        }
        bounds[tid] = lo;
    }
    __syncthreads();
    int lo = bounds[0], hi = bounds[1];
    int cnt = hi - lo;

    float s = 0.f;
    for (int nd = lo + wave; nd < hi; nd += 4)
        s += x[(size_t)nd * 64 + lane];
    psum[wave][lane] = s;
    __syncthreads();

    if (tid < 64)
        gv[tid] = (psum[0][tid] + psum[1][tid] + psum[2][tid] + psum[3][tid])
                  / fmaxf((float)cnt, 1.0f);
    __syncthreads();

    if (tid < 128) {
        float h = b1[tid];
        for (int k = 0; k < 64; k++) h += gv[k] * W1[k * 128 + tid];
        hid[tid] = fmaxf(h, 0.f);
    }
    __syncthreads();
    if (tid < 128) {
        float o = b2[tid];
        for (int k = 0; k < 128; k++) o += hid[k] * W2[k * 128 + tid];
        out[g * 128 + tid] = o;
    }
}

// ---------------- launch ----------------

extern "C" void kernel_launch(void* const* d_in, const int* in_sizes, int n_in,
                              void* d_out, int out_size, void* d_ws, size_t ws_size,
                              hipStream_t stream) {
    const float* nf   = (const float*)d_in[0];
    const int*   ei   = (const int*)d_in[1];
    const float* eaw  = (const float*)d_in[2];
    const int*   bat  = (const int*)d_in[3];
    const float* l0_Wl = (const float*)d_in[4];
    const float* l0_bl = (const float*)d_in[5];
    const float* l0_Wr = (const float*)d_in[6];
    const float* l0_br = (const float*)d_in[7];
    const float* l0_We = (const float*)d_in[8];
    const float* l0_att = (const float*)d_in[9];
    const float* l0_bias = (const float*)d_in[10];
    const float* l1_Wl = (const float*)d_in[11];
    const float* l1_bl = (const float*)d_in[12];
    const float* l1_Wr = (const float*)d_in[13];
    const float* l1_br = (const float*)d_in[14];
    const float* l1_We = (const float*)d_in[15];
    const float* l1_att = (const float*)d_in[16];
    const float* l1_bias = (const float*)d_in[17];
    const float* mW1 = (const float*)d_in[18];
    const float* mb1 = (const float*)d_in[19];
    const float* mW2 = (const float*)d_in[20];
    const float* mb2 = (const float*)d_in[21];

    const int N = in_sizes[0] / 64;
    const int E = in_sizes[1] / 2;
    const int G = out_size / OUTD;

    char* w = (char*)d_ws;
    auto carve = [&](size_t bytes) {
        void* p = (void*)w;
        w += (bytes + 255) & ~(size_t)255;
        return p;
    };
    int*   deg     = (int*)carve((size_t)N * 4);
    int*   offs    = (int*)carve((size_t)(N + 1) * 4);
    int*   cursor  = (int*)carve((size_t)N * 4);
    int*   bsum    = (int*)carve(4096 * 4);
    int4*  csr     = (int4*)carve((size_t)(E + N) * 16);
    float* la      = (float*)carve((size_t)N * EDIM * 4);
    float* xl      = (float*)carve((size_t)N * 64 * 4);
    float* xr      = (float*)carve((size_t)N * 64 * 4);
    float* x1      = (float*)carve((size_t)N * 64 * 4);   // layer0 out, then layer1 out

    hipMemsetAsync(deg, 0, (size_t)N * 4, stream);
    hipMemsetAsync(cursor, 0, (size_t)N * 4, stream);

    const int* src = ei;
    const int* dst = ei + E;

    hist_kernel<<<(E + 255) / 256, 256, 0, stream>>>(dst, deg, E);

    int nb = (N + 1023) / 1024;
    scan_a<<<nb, 1024, 0, stream>>>(deg, offs, bsum, N);
    scan_b<<<1, 1024, 0, stream>>>(bsum, offs, nb, N);
    scan_c<<<nb, 1024, 0, stream>>>(offs, bsum, N);

    scatter_kernel<<<(E + 255) / 256, 256, 0, stream>>>(src, dst, eaw, offs, cursor,
                                                        csr, E);
    loopattr_kernel<<<(N * EDIM + 255) / 256, 256, 0, stream>>>(offs, csr, la, N);

    // layer 0
    dualgemm_kernel<<<(N + 63) / 64, 256, 0, stream>>>(nf, l0_Wl, l0_bl, l0_Wr, l0_br,
                                                       xl, xr, N);
    gat_kernel<<<(N + 3) / 4, 256, 0, stream>>>(offs, csr, xl, xr,
                                                l0_We, l0_att, l0_bias, x1, N);
    // layer 1
    dualgemm_kernel<<<(N + 63) / 64, 256, 0, stream>>>(x1, l1_Wl, l1_bl, l1_Wr, l1_br,
                                                       xl, xr, N);
    gat_kernel<<<(N + 3) / 4, 256, 0, stream>>>(offs, csr, xl, xr,
                                                l1_We, l1_att, l1_bias, x1, N);

    // fused pool + MLP
    pool_mlp_kernel<<<G, 256, 0, stream>>>(x1, bat, N, mW1, mb1, mW2, mb2, (float*)d_out);
}

// Round 4
// 926.531 us; speedup vs baseline: 1.1814x; 1.1814x over previous
//
#include <hip/hip_runtime.h>
#include <math.h>

// Problem constants (from reference)
#define HID 64      // H*C
#define NH 4
#define NC 16
#define EDIM 16
#define OUTD 128
#define NEG 0.2f

// CSR: slot p has csr_src[p] (source node) and csr_ea[p] (16 floats, 64B).
// Slot offs[d] is the self-loop (attr = mean of in-edge attrs); offs[d]+1.. in-edges.

// ---------------- CSR build ----------------

__global__ void hist_kernel(const int* __restrict__ dst, int* __restrict__ deg, int E) {
    int e = blockIdx.x * 256 + threadIdx.x;
    if (e < E) atomicAdd(&deg[dst[e]], 1);
}

__global__ void scan_a(const int* __restrict__ deg, int* __restrict__ offs,
                       int* __restrict__ bsum, int n) {
    __shared__ int tmp[1024];
    int i = blockIdx.x * 1024 + threadIdx.x;
    int v = (i < n) ? (deg[i] + 1) : 0;      // +1: self-loop slot
    tmp[threadIdx.x] = v;
    __syncthreads();
    for (int off = 1; off < 1024; off <<= 1) {
        int t = (threadIdx.x >= off) ? tmp[threadIdx.x - off] : 0;
        __syncthreads();
        tmp[threadIdx.x] += t;
        __syncthreads();
    }
    if (i < n) offs[i] = tmp[threadIdx.x] - v;   // exclusive
    if (threadIdx.x == 1023) bsum[blockIdx.x] = tmp[1023];
}

__global__ void scan_b(int* __restrict__ bsum, int* __restrict__ offs, int nb, int n) {
    __shared__ int tmp[1024];
    int v = (threadIdx.x < nb) ? bsum[threadIdx.x] : 0;
    tmp[threadIdx.x] = v;
    __syncthreads();
    for (int off = 1; off < 1024; off <<= 1) {
        int t = (threadIdx.x >= off) ? tmp[threadIdx.x - off] : 0;
        __syncthreads();
        tmp[threadIdx.x] += t;
        __syncthreads();
    }
    if (threadIdx.x < nb) bsum[threadIdx.x] = tmp[threadIdx.x] - v;  // exclusive
    if (threadIdx.x == 1023) offs[n] = tmp[1023];                    // total = E + N
}

__global__ void scan_c(int* __restrict__ offs, const int* __restrict__ bsum, int n) {
    int i = blockIdx.x * 1024 + threadIdx.x;
    if (i < n) offs[i] += bsum[blockIdx.x];
}

// scatter: fill in-edge slots; copy edge attr into CSR order (sequential read,
// random 64B write — paid once, read sequentially twice)
__global__ void scatter_kernel(const int* __restrict__ src, const int* __restrict__ dst,
                               const float4* __restrict__ ea,
                               const int* __restrict__ offs, int* __restrict__ cursor,
                               int* __restrict__ csr_src, float4* __restrict__ csr_ea,
                               int E) {
    int e = blockIdx.x * 256 + threadIdx.x;
    if (e >= E) return;
    int d = dst[e];
    int p = offs[d] + 1 + atomicAdd(&cursor[d], 1);
    csr_src[p] = src[e];
    float4 a0 = ea[e * 4 + 0], a1 = ea[e * 4 + 1],
           a2 = ea[e * 4 + 2], a3 = ea[e * 4 + 3];
    csr_ea[p * 4 + 0] = a0;
    csr_ea[p * 4 + 1] = a1;
    csr_ea[p * 4 + 2] = a2;
    csr_ea[p * 4 + 3] = a3;
}

// self-loop slot: attr = mean of in-edge attrs (0 if none), src = node itself
__global__ void loopattr_kernel(const int* __restrict__ offs, int* __restrict__ csr_src,
                                float* __restrict__ csr_ea_f, int n) {
    int idx = blockIdx.x * 256 + threadIdx.x;
    if (idx >= n * EDIM) return;
    int nd = idx >> 4, k = idx & 15;
    int e0 = offs[nd], e1 = offs[nd + 1];
    int deg = e1 - e0 - 1;
    float s = 0.f;
    for (int j = e0 + 1; j < e1; j++) s += csr_ea_f[(size_t)j * EDIM + k];
    csr_ea_f[(size_t)e0 * EDIM + k] = s / fmaxf((float)deg, 1.0f);
    if (k == 0) csr_src[e0] = nd;
}

// ---------------- dual GEMM: xl = x@Wl+bl, xr = x@Wr+br ----------------

__global__ __launch_bounds__(256)
void dualgemm_kernel(const float* __restrict__ x,
                     const float* __restrict__ Wl, const float* __restrict__ bl,
                     const float* __restrict__ Wr, const float* __restrict__ br,
                     float* __restrict__ xl, float* __restrict__ xr, int n) {
    __shared__ float xs[64 * 65];     // [row][k], pad 65
    __shared__ float ws[64 * 128];    // [k][j]: j<64 -> Wl col, j>=64 -> Wr col
    int tid = threadIdx.x;
    int r0 = blockIdx.x * 64;

#pragma unroll
    for (int t = 0; t < 32; t++) {
        int idx = t * 256 + tid;
        int k = idx >> 7, j = idx & 127;
        ws[idx] = (j < 64) ? Wl[k * 64 + j] : Wr[k * 64 + (j - 64)];
    }
#pragma unroll
    for (int t = 0; t < 16; t++) {
        int idx = t * 256 + tid;
        int r = idx >> 6, c = idx & 63;
        float v = (r0 + r < n) ? x[(r0 + r) * 64 + c] : 0.f;
        xs[r * 65 + c] = v;
    }
    __syncthreads();

    int cg = tid & 31;
    int rg = tid >> 5;

    float acc[8][4];
#pragma unroll
    for (int u = 0; u < 8; u++)
#pragma unroll
        for (int v = 0; v < 4; v++) acc[u][v] = 0.f;

    for (int k = 0; k < 64; k++) {
        float4 wv = *(const float4*)&ws[k * 128 + cg * 4];
        float xv[8];
#pragma unroll
        for (int u = 0; u < 8; u++) xv[u] = xs[(rg * 8 + u) * 65 + k];
#pragma unroll
        for (int u = 0; u < 8; u++) {
            acc[u][0] += xv[u] * wv.x;
            acc[u][1] += xv[u] * wv.y;
            acc[u][2] += xv[u] * wv.z;
            acc[u][3] += xv[u] * wv.w;
        }
    }

    int j0 = cg * 4;
    bool isL = (j0 < 64);
    const float* bp = isL ? bl : br;
    float* op = isL ? xl : xr;
    int jj = isL ? j0 : (j0 - 64);
    float4 bv = *(const float4*)&bp[jj];
#pragma unroll
    for (int u = 0; u < 8; u++) {
        int r = r0 + rg * 8 + u;
        if (r < n) {
            float4 o;
            o.x = acc[u][0] + bv.x; o.y = acc[u][1] + bv.y;
            o.z = acc[u][2] + bv.z; o.w = acc[u][3] + bv.w;
            *(float4*)&op[r * 64 + jj] = o;
        }
    }
}

// ---------------- GATv2 layer ----------------
// One wave per dst node, lane = h*16+c. Attr loads are sequential in slot index
// (no address dependence); src gather software-pipelined one pair ahead.

#define DOT16(P0, P1, P2, P3)                                              \
    (P0.x*wec[0] + P0.y*wec[1] + P0.z*wec[2] + P0.w*wec[3]                 \
   + P1.x*wec[4] + P1.y*wec[5] + P1.z*wec[6] + P1.w*wec[7]                 \
   + P2.x*wec[8] + P2.y*wec[9] + P2.z*wec[10] + P2.w*wec[11]               \
   + P3.x*wec[12] + P3.y*wec[13] + P3.z*wec[14] + P3.w*wec[15])

__global__ __launch_bounds__(256)
void gat_kernel(const int* __restrict__ offs, const int* __restrict__ csr_src,
                const float4* __restrict__ csr_ea,
                const float* __restrict__ xl, const float* __restrict__ xr,
                const float* __restrict__ We, const float* __restrict__ att,
                const float* __restrict__ bias, float* __restrict__ out, int n) {
    int lane = threadIdx.x & 63;
    int node = __builtin_amdgcn_readfirstlane(blockIdx.x * 4 + (threadIdx.x >> 6));
    if (node >= n) return;

    float wec[16];
#pragma unroll
    for (int k = 0; k < 16; k++) wec[k] = We[k * 64 + lane];
    const float LOG2E = 1.4426950408889634f;
    float attl = att[lane] * LOG2E;
    float xrl = xr[(size_t)node * 64 + lane];

    int e0 = __builtin_amdgcn_readfirstlane(offs[node]);
    int e1 = __builtin_amdgcn_readfirstlane(offs[node + 1]);

    float M = -1e30f, S = 0.f, acc = 0.f;
    int i = e0;

    if ((e1 - e0) & 1) {            // odd count: process slot e0 (self-loop) alone
        int s0 = csr_src[i];
        float4 A0 = csr_ea[i*4+0], A1 = csr_ea[i*4+1],
               A2 = csr_ea[i*4+2], A3 = csr_ea[i*4+3];
        float x0 = xl[(size_t)s0 * 64 + lane];
        float m0 = x0 + xrl + DOT16(A0, A1, A2, A3);
        m0 = fmaxf(m0, NEG * m0);
        float p0 = m0 * attl;
        p0 += __shfl_xor(p0, 1);
        p0 += __shfl_xor(p0, 2);
        p0 += __shfl_xor(p0, 4);
        p0 += __shfl_xor(p0, 8);
        M = p0; S = 1.f; acc = x0;   // first edge: z=1
        i++;
    }

    if (i < e1) {
        // prologue: load pair i
        int sa = csr_src[i], sb = csr_src[i + 1];
        float4 A0 = csr_ea[i*4+0], A1 = csr_ea[i*4+1],
               A2 = csr_ea[i*4+2], A3 = csr_ea[i*4+3];
        float4 B0 = csr_ea[i*4+4], B1 = csr_ea[i*4+5],
               B2 = csr_ea[i*4+6], B3 = csr_ea[i*4+7];
        float xa = xl[(size_t)sa * 64 + lane];
        float xb = xl[(size_t)sb * 64 + lane];
        for (;;) {
            int j = i + 2;
            bool more = (j < e1);
            int sa_n, sb_n;
            float4 A0n, A1n, A2n, A3n, B0n, B1n, B2n, B3n;
            float xa_n, xb_n;
            if (more) {               // prefetch next pair (overlaps compute below)
                sa_n = csr_src[j]; sb_n = csr_src[j + 1];
                A0n = csr_ea[j*4+0]; A1n = csr_ea[j*4+1];
                A2n = csr_ea[j*4+2]; A3n = csr_ea[j*4+3];
                B0n = csr_ea[j*4+4]; B1n = csr_ea[j*4+5];
                B2n = csr_ea[j*4+6]; B3n = csr_ea[j*4+7];
                xa_n = xl[(size_t)sa_n * 64 + lane];
                xb_n = xl[(size_t)sb_n * 64 + lane];
            }
            // compute current pair
            float m0 = xa + xrl + DOT16(A0, A1, A2, A3);
            float m1 = xb + xrl + DOT16(B0, B1, B2, B3);
            m0 = fmaxf(m0, NEG * m0);
            m1 = fmaxf(m1, NEG * m1);
            float p0 = m0 * attl;
            float p1 = m1 * attl;
            p0 += __shfl_xor(p0, 1);  p1 += __shfl_xor(p1, 1);
            p0 += __shfl_xor(p0, 2);  p1 += __shfl_xor(p1, 2);
            p0 += __shfl_xor(p0, 4);  p1 += __shfl_xor(p1, 4);
            p0 += __shfl_xor(p0, 8);  p1 += __shfl_xor(p1, 8);
            float Mn = fmaxf(M, fmaxf(p0, p1));
            float fs = __builtin_amdgcn_exp2f(M - Mn);
            float z0 = __builtin_amdgcn_exp2f(p0 - Mn);
            float z1 = __builtin_amdgcn_exp2f(p1 - Mn);
            S   = S * fs + z0 + z1;
            acc = acc * fs + z0 * xa + z1 * xb;
            M = Mn;
            if (!more) break;
            sa = sa_n; sb = sb_n;
            A0 = A0n; A1 = A1n; A2 = A2n; A3 = A3n;
            B0 = B0n; B1 = B1n; B2 = B2n; B3 = B3n;
            xa = xa_n; xb = xb_n;
            i = j;
        }
    }
    out[(size_t)node * 64 + lane] = fmaxf(acc / S + bias[lane], 0.f);
}

// ---------------- fused pool (batch is sorted) + MLP: one block per graph ----------------

__global__ __launch_bounds__(256)
void pool_mlp_kernel(const float* __restrict__ x, const int* __restrict__ batch, int n,
                     const float* __restrict__ W1, const float* __restrict__ b1,
                     const float* __restrict__ W2, const float* __restrict__ b2,
                     float* __restrict__ out) {
    __shared__ float psum[4][64];
    __shared__ float gv[64];
    __shared__ float hid[128];
    __shared__ int bounds[2];

    int g = blockIdx.x;
    int tid = threadIdx.x;
    int wave = tid >> 6, lane = tid & 63;

    if (tid < 2) {
        int target = g + tid;
        int lo = 0, hi = n;
        while (lo < hi) {
            int mid = (lo + hi) >> 1;
            if (batch[mid] < target) lo = mid + 1; else hi = mid;
        }
        bounds[tid] = lo;
    }
    __syncthreads();
    int lo = bounds[0], hi = bounds[1];
    int cnt = hi - lo;

    float s = 0.f;
    for (int nd = lo + wave; nd < hi; nd += 4)
        s += x[(size_t)nd * 64 + lane];
    psum[wave][lane] = s;
    __syncthreads();

    if (tid < 64)
        gv[tid] = (psum[0][tid] + psum[1][tid] + psum[2][tid] + psum[3][tid])
                  / fmaxf((float)cnt, 1.0f);
    __syncthreads();

    if (tid < 128) {
        float h = b1[tid];
        for (int k = 0; k < 64; k++) h += gv[k] * W1[k * 128 + tid];
        hid[tid] = fmaxf(h, 0.f);
    }
    __syncthreads();
    if (tid < 128) {
        float o = b2[tid];
        for (int k = 0; k < 128; k++) o += hid[k] * W2[k * 128 + tid];
        out[g * 128 + tid] = o;
    }
}

// ---------------- launch ----------------

extern "C" void kernel_launch(void* const* d_in, const int* in_sizes, int n_in,
                              void* d_out, int out_size, void* d_ws, size_t ws_size,
                              hipStream_t stream) {
    const float* nf   = (const float*)d_in[0];
    const int*   ei   = (const int*)d_in[1];
    const float* eaw  = (const float*)d_in[2];
    const int*   bat  = (const int*)d_in[3];
    const float* l0_Wl = (const float*)d_in[4];
    const float* l0_bl = (const float*)d_in[5];
    const float* l0_Wr = (const float*)d_in[6];
    const float* l0_br = (const float*)d_in[7];
    const float* l0_We = (const float*)d_in[8];
    const float* l0_att = (const float*)d_in[9];
    const float* l0_bias = (const float*)d_in[10];
    const float* l1_Wl = (const float*)d_in[11];
    const float* l1_bl = (const float*)d_in[12];
    const float* l1_Wr = (const float*)d_in[13];
    const float* l1_br = (const float*)d_in[14];
    const float* l1_We = (const float*)d_in[15];
    const float* l1_att = (const float*)d_in[16];
    const float* l1_bias = (const float*)d_in[17];
    const float* mW1 = (const float*)d_in[18];
    const float* mb1 = (const float*)d_in[19];
    const float* mW2 = (const float*)d_in[20];
    const float* mb2 = (const float*)d_in[21];

    const int N = in_sizes[0] / 64;
    const int E = in_sizes[1] / 2;
    const int G = out_size / OUTD;

    char* w = (char*)d_ws;
    auto carve = [&](size_t bytes) {
        void* p = (void*)w;
        w += (bytes + 255) & ~(size_t)255;
        return p;
    };
    int*    deg     = (int*)carve((size_t)N * 4);
    int*    offs    = (int*)carve((size_t)(N + 1) * 4);
    int*    cursor  = (int*)carve((size_t)N * 4);
    int*    bsum    = (int*)carve(4096 * 4);
    int*    csr_src = (int*)carve((size_t)(E + N) * 4);
    float4* csr_ea  = (float4*)carve((size_t)(E + N) * 64);
    float*  xl      = (float*)carve((size_t)N * 64 * 4);
    float*  xr      = (float*)carve((size_t)N * 64 * 4);
    float*  x1      = (float*)carve((size_t)N * 64 * 4);

    hipMemsetAsync(deg, 0, (size_t)N * 4, stream);
    hipMemsetAsync(cursor, 0, (size_t)N * 4, stream);

    const int* src = ei;
    const int* dst = ei + E;

    hist_kernel<<<(E + 255) / 256, 256, 0, stream>>>(dst, deg, E);

    int nb = (N + 1023) / 1024;
    scan_a<<<nb, 1024, 0, stream>>>(deg, offs, bsum, N);
    scan_b<<<1, 1024, 0, stream>>>(bsum, offs, nb, N);
    scan_c<<<nb, 1024, 0, stream>>>(offs, bsum, N);

    scatter_kernel<<<(E + 255) / 256, 256, 0, stream>>>(src, dst, (const float4*)eaw,
                                                        offs, cursor, csr_src, csr_ea, E);
    loopattr_kernel<<<(N * EDIM + 255) / 256, 256, 0, stream>>>(offs, csr_src,
                                                                (float*)csr_ea, N);

    // layer 0
    dualgemm_kernel<<<(N + 63) / 64, 256, 0, stream>>>(nf, l0_Wl, l0_bl, l0_Wr, l0_br,
                                                       xl, xr, N);
    gat_kernel<<<(N + 3) / 4, 256, 0, stream>>>(offs, csr_src, csr_ea, xl, xr,
                                                l0_We, l0_att, l0_bias, x1, N);
    // layer 1
    dualgemm_kernel<<<(N + 63) / 64, 256, 0, stream>>>(x1, l1_Wl, l1_bl, l1_Wr, l1_br,
                                                       xl, xr, N);
    gat_kernel<<<(N + 3) / 4, 256, 0, stream>>>(offs, csr_src, csr_ea, xl, xr,
                                                l1_We, l1_att, l1_bias, x1, N);

    // fused pool + MLP
    pool_mlp_kernel<<<G, 256, 0, stream>>>(x1, bat, N, mW1, mb1, mW2, mb2, (float*)d_out);
}